// Round 22
// baseline (623.942 us; speedup 1.0000x reference)
//
#include <hip/hip_runtime.h>

// CGCConv: out = (scatter_add(ew*pr[src]*x[src], dst) + x) @ W.T + b
// N=50000, E=800000, D=96, fp32.
//
// Session 2 / Round 22. R21 (per-wave hist+shfl scan): 136.6, real but
// tiny (-1.9 vs predicted -12-18) => sort's 34us is NOT contention/
// barriers; it's the structure (solo-residency chains + stage round-trip
// + second pass). Ledger: F~69, sort 34.4, pull 25.2, gemm 8.
// CHANGE: kill sortB AND pull. k_aggr = one block per 128-node bucket:
// stream unsorted bucket edges (coalesced u64 entries), per edge 48 lanes
// read the 192B y16[src] row COALESCED and ds_add_f32 into LDS
// aggr[128][96] (49KB, 3 blocks/CU); write-out pass = bf16(aggr+x).
// Replaces sortB's sort+rewrite+reread and pull's 9.6M random 16B gathers.
// NB 196->391 (dst>>7); prep scan widened to 512 bins / 8-wave (mechanical
// ext of R21-verified code); cvt/wfrag ride in prep grid.
// Pipeline (3 kernels): memset(cur1) -> prep(bin|cvt|Wfrag) -> aggr -> gemm.
// Prediction: aggr ~10-15 replacing 42 => dur ~105-118. absmax ~0.0625
// (atomic sum-order noise). Failure: aggr>=25 => revert to 136.6 + x5 split.

constexpr int NN = 50000;
constexpr int NE = 800000;
constexpr int DD = 96;
constexpr int NB = 391;                       // buckets: dst>>7 (128 nodes)
constexpr int BKN = 128;                      // nodes per bucket
constexpr int CAPB = 2560;                    // mu=2046 + ~11 sigma
constexpr int EPB = 4096;                     // edges per prep block
constexpr int NBLK = (NE + EPB - 1) / EPB;    // 196
constexpr int NCVT = (NN * DD / 4 + 511) / 512;  // 2344 cvt blocks

using s8v = __attribute__((ext_vector_type(8))) short;   // 8 bf16
using f4v = __attribute__((ext_vector_type(4))) float;   // 4 fp32
using u16x8 = __attribute__((ext_vector_type(8))) unsigned short;  // 16B

__device__ inline unsigned short f2bf(float f) {    // RNE fp32->bf16
    unsigned u = __float_as_uint(f);
    return (unsigned short)((u + 0x7FFFu + ((u >> 16) & 1u)) >> 16);
}
__device__ inline float bfh(unsigned short v) {
    return __uint_as_float((unsigned)v << 16);
}
__device__ inline unsigned long long pack_e(int meta, float c) {
    return (unsigned long long)(unsigned)meta |
           ((unsigned long long)(unsigned)__float_as_uint(c) << 32);
}

// Blocks [0,NBLK): bin 4096 edges by 512 buckets (per-wave hist + 8-wave
// shfl scan, R21-verified pattern) -> coalesced run writes to stage.
// Entry u64 = {src:16 | dloc:7 | bucket:9 | coef_f32:32}.
// Blocks [NBLK,NBLK+NCVT): y16 = bf16(x). Block NBLK+NCVT: W -> wfrag.
__global__ __launch_bounds__(512) void k_prep(const int* __restrict__ src,
                                              const int* __restrict__ dst,
                                              const float* __restrict__ ew,
                                              const float* __restrict__ pr,
                                              int* __restrict__ cur1,
                                              unsigned long long* __restrict__ stage,
                                              const float4* __restrict__ x4,
                                              ushort4* __restrict__ y16v,
                                              const float* __restrict__ W,
                                              unsigned short* __restrict__ wfrag) {
    int tid = threadIdx.x;
    int blk = blockIdx.x;
    if (blk >= NBLK) {
        int ci = blk - NBLK;
        if (ci < NCVT) {                        // cvt phase
            int i = ci * 512 + tid;
            if (i < NN * DD / 4) {
                float4 v = x4[i];
                y16v[i] = make_ushort4(f2bf(v.x), f2bf(v.y), f2bf(v.z), f2bf(v.w));
            }
        } else {                                // W fragment phase (1 block)
            for (int i = tid; i < 18 * 512; i += 512) {
                int f = i >> 9, r = i & 511;
                int lane = r >> 3, j = r & 7;
                int ks = f / 6, nt = f - 6 * ks;
                int n = nt * 16 + (lane & 15);
                int k = ks * 32 + (lane >> 4) * 8 + j;
                wfrag[i] = f2bf(W[n * DD + k]);
            }
        }
        return;
    }
    int wv = tid >> 6, ln = tid & 63;
    __shared__ int h[8][512];                    // per-wave histograms, 16KB
    __shared__ int tot[512];
    __shared__ int sc[512];
    __shared__ int gb[512];
    __shared__ int wsum[8];
    __shared__ unsigned long long sorted[EPB];   // 32 KB

    for (int i = ln; i < 512; i += 64) h[wv][i] = 0;  // own table: no barrier
    int base = blockIdx.x * EPB;
    int n = min(EPB, NE - base);

    unsigned long long ent[8]; int bkt[8]; int lrk[8];
    #pragma unroll
    for (int j = 0; j < 8; j++) {
        int e = base + j * 512 + tid;
        bkt[j] = -1;
        if (e < NE) {
            int d = dst[e];
            int s = src[e];
            float c = ew[e] * pr[s];
            int bk = d >> 7;
            bkt[j] = bk;
            lrk[j] = atomicAdd(&h[wv][bk], 1);   // own-wave table
            ent[j] = pack_e(s | ((d & 127) << 16) | (bk << 23), c);
        }
    }
    __syncthreads();                             // B1: histograms complete
    int run = 0;                                 // cross-wave prefix, in-place
    #pragma unroll
    for (int w = 0; w < 8; w++) { int v = h[w][tid]; h[w][tid] = run; run += v; }
    tot[tid] = run;
    int scv = run;                               // wave-intrinsic inclusive scan
    #pragma unroll
    for (int o = 1; o < 64; o <<= 1) {
        int t = __shfl_up(scv, o);
        if (ln >= o) scv += t;
    }
    if (ln == 63) wsum[wv] = scv;
    __syncthreads();                             // B2: wsum ready
    int add = 0;
    #pragma unroll
    for (int w = 0; w < 8; w++) add += (w < wv) ? wsum[w] : 0;
    sc[tid] = scv + add;
    if (tid < NB)
        gb[tid] = tot[tid] ? atomicAdd(&cur1[tid], tot[tid]) : 0;
    __syncthreads();                             // B3: sc/gb ready
    #pragma unroll
    for (int j = 0; j < 8; j++)
        if (bkt[j] >= 0)
            sorted[sc[bkt[j]] - tot[bkt[j]] + h[wv][bkt[j]] + lrk[j]] = ent[j];
    __syncthreads();                             // B4: sorted ready
    for (int i = tid; i < n; i += 512) {         // coalesced run writes
        unsigned long long e = sorted[i];
        int bk = ((int)(e >> 23)) & 0x1ff;
        stage[(size_t)bk * CAPB + gb[bk] + (i - (sc[bk] - tot[bk]))] = e;
    }
}

// Aggregate: one block per 128-node bucket. Stream the bucket's unsorted
// edges; per edge, 48 lanes read the 192B y16[src] row coalesced (u32 = 2
// bf16 each) and ds_add_f32 into aggr[dloc][ch]. Then io16 = bf16(aggr+x).
__global__ __launch_bounds__(512) void k_aggr(const unsigned long long* __restrict__ stage,
                                              const int* __restrict__ cur1,
                                              const unsigned short* __restrict__ y16,
                                              const float4* __restrict__ x4,
                                              u16x8* __restrict__ io16v8) {
    __shared__ float aggr[BKN][DD];              // 49.2 KB -> 3 blocks/CU
    int tid = threadIdx.x;
    int wv = tid >> 6, ln = tid & 63;
    int b = blockIdx.x;
    size_t base = (size_t)b * CAPB;
    int n = cur1[b];

    float* af = &aggr[0][0];
    for (int s = tid; s < BKN * DD; s += 512) af[s] = 0.f;
    __syncthreads();

    int ch = 2 * ln;                             // lanes 0..47 own 2 channels
    int i = wv;
    for (; i + 8 < n; i += 16) {                 // 2-deep for ILP
        unsigned long long e0 = stage[base + i];
        unsigned long long e1 = stage[base + i + 8];
        if (ln < 48) {
            unsigned p0 = *(const unsigned*)(y16 + (size_t)(e0 & 0xffff) * DD + ch);
            unsigned p1 = *(const unsigned*)(y16 + (size_t)(e1 & 0xffff) * DD + ch);
            int d0 = ((int)(e0 >> 16)) & 0x7f;
            int d1 = ((int)(e1 >> 16)) & 0x7f;
            float c0 = __uint_as_float((unsigned)(e0 >> 32));
            float c1 = __uint_as_float((unsigned)(e1 >> 32));
            atomicAdd(&aggr[d0][ch],     c0 * bfh((unsigned short)p0));
            atomicAdd(&aggr[d0][ch + 1], c0 * bfh((unsigned short)(p0 >> 16)));
            atomicAdd(&aggr[d1][ch],     c1 * bfh((unsigned short)p1));
            atomicAdd(&aggr[d1][ch + 1], c1 * bfh((unsigned short)(p1 >> 16)));
        }
    }
    for (; i < n; i += 8) {
        unsigned long long e = stage[base + i];
        if (ln < 48) {
            unsigned pp = *(const unsigned*)(y16 + (size_t)(e & 0xffff) * DD + ch);
            int dl = ((int)(e >> 16)) & 0x7f;
            float c = __uint_as_float((unsigned)(e >> 32));
            atomicAdd(&aggr[dl][ch],     c * bfh((unsigned short)pp));
            atomicAdd(&aggr[dl][ch + 1], c * bfh((unsigned short)(pp >> 16)));
        }
    }
    __syncthreads();

    for (int s = tid; s < BKN * 12; s += 512) {  // write io16 = bf16(aggr+x)
        int nl = s / 12, q = s - nl * 12;        // node-local, u16x8 slot
        int g = (b << 7) + nl;
        if (g < NN) {
            float4 xl = x4[(size_t)g * 24 + q * 2];
            float4 xh = x4[(size_t)g * 24 + q * 2 + 1];
            const float* a = &aggr[nl][q * 8];
            u16x8 o;
            o[0] = f2bf(a[0] + xl.x); o[1] = f2bf(a[1] + xl.y);
            o[2] = f2bf(a[2] + xl.z); o[3] = f2bf(a[3] + xl.w);
            o[4] = f2bf(a[4] + xh.x); o[5] = f2bf(a[5] + xh.y);
            o[6] = f2bf(a[6] + xh.z); o[7] = f2bf(a[7] + xh.w);
            io16v8[(size_t)g * 12 + q] = o;
        }
    }
}

// MFMA GEMM: out[r,o] = sum_d io16[r,d]*W[o,d] + b[o], fp32 out.
// B-frags pre-swizzled in ws (wfrag), loaded coalesced 16B/lane from L2.
// C/D: col=lane&15, row=quad*4+reg (HW-verified; absmax-confirmed).
__global__ __launch_bounds__(256) void k_gemm(const unsigned short* __restrict__ io16,
                                              const unsigned short* __restrict__ wfrag,
                                              const float* __restrict__ b,
                                              float* __restrict__ out) {
    int tid = threadIdx.x;
    int wave = tid >> 6, lane = tid & 63;
    int quad = lane >> 4, m16 = lane & 15;
    int r0 = blockIdx.x * 64 + wave * 16;
    int rowa = r0 + m16;
    if (rowa >= NN) rowa = NN - 1;           // clamped A read, store masked

    const s8v* wf = (const s8v*)wfrag;       // frag (ks*6+nt) x 64 lanes

    f4v acc[6];
    #pragma unroll
    for (int nt = 0; nt < 6; nt++) acc[nt] = (f4v){0.f, 0.f, 0.f, 0.f};

    #pragma unroll
    for (int ks = 0; ks < 3; ks++) {
        s8v a = *(const s8v*)(io16 + (size_t)rowa * DD + ks * 32 + quad * 8);
        #pragma unroll
        for (int nt = 0; nt < 6; nt++) {
            s8v bb = wf[(ks * 6 + nt) * 64 + lane];
            acc[nt] = __builtin_amdgcn_mfma_f32_16x16x32_bf16(a, bb, acc[nt], 0, 0, 0);
        }
    }

    #pragma unroll
    for (int nt = 0; nt < 6; nt++) {
        float bias = b[nt * 16 + m16];
        #pragma unroll
        for (int reg = 0; reg < 4; reg++) {
            int rr = r0 + quad * 4 + reg;
            if (rr < NN)
                out[(size_t)rr * DD + nt * 16 + m16] = acc[nt][reg] + bias;
        }
    }
}

extern "C" void kernel_launch(void* const* d_in, const int* in_sizes, int n_in,
                              void* d_out, int out_size, void* d_ws, size_t ws_size,
                              hipStream_t stream) {
    const float* x  = (const float*)d_in[0];
    const int*   ei = (const int*)d_in[1];   // [2,E]: [0..E)=src, [E..2E)=dst
    const float* ew = (const float*)d_in[2];
    const float* pr = (const float*)d_in[3];
    const float* W  = (const float*)d_in[4];
    const float* b  = (const float*)d_in[5];
    float* out = (float*)d_out;

    // ws layout (~27.3 MB)
    unsigned long long* stage = (unsigned long long*)d_ws;       // NB*CAPB u64 = 8.0MB
    unsigned short* y16 = (unsigned short*)(stage + (size_t)NB * CAPB);  // 9.6MB
    int* cur1 = (int*)(y16 + (size_t)NN * DD);        // 391
    unsigned short* io16 = (unsigned short*)(cur1 + 512);        // 9.6MB
    unsigned short* wfrag = io16 + (size_t)NN * DD;   // 18*512 bf16 = 18.4KB

    const int* src = ei;
    const int* dst = ei + NE;

    hipMemsetAsync(cur1, 0, NB * sizeof(int), stream);
    k_prep<<<NBLK + NCVT + 1, 512, 0, stream>>>(src, dst, ew, pr, cur1, stage,
                                                (const float4*)x, (ushort4*)y16,
                                                W, wfrag);
    k_aggr<<<NB, 512, 0, stream>>>(stage, cur1, y16, (const float4*)x,
                                   (u16x8*)io16);
    k_gemm<<<(NN + 63) / 64, 256, 0, stream>>>(io16, wfrag, b, out);
}

// Round 24
// 138.692 us; speedup vs baseline: 4.4988x; 4.4988x over previous
//
#include <hip/hip_runtime.h>

// CGCConv: out = (scatter_add(ew*pr[src]*x[src], dst) + x) @ W.T + b
// N=50000, E=800000, D=96, fp32.
//
// Session 2 / Round 24: RESUBMIT REVERT to R21-verified best (136.6us) —
// R23 revert hit broker timeout; last measured state is R22's 623.9us
// k_aggr failure, so restoring the verified state takes priority.
// R22 lesson (with R15): the hot kernels are latency-machines — never
// trade TLP for traffic. Ledger: F~69 harness-fixed (268MB ws re-poison
// in-window + memset + gaps), sort 34.4 (per-wave hist + shfl-scan, R21),
// pull 25.2 (16B gather, R17), gemm ~8. Intra-sort tweaks exhausted;
// both sort-replacement structures regressed; pull near latency floor.
// Pipeline: memset(cur1) -> prep(bin) -> sortB(sort|cvt|Wfrag) -> pull -> gemm.

constexpr int NN = 50000;
constexpr int NE = 800000;
constexpr int DD = 96;
constexpr int NB = 196;                       // buckets: dst>>8 (256 nodes)
constexpr int CAPB = 4608;                    // mu=4082 + 8 sigma
constexpr int EPB = 4096;                     // edges per binA block
constexpr int NBLK = (NE + EPB - 1) / EPB;    // 196
constexpr int NCVT = (NN * DD / 4 + 511) / 512;  // 2344 cvt blocks

using s8v = __attribute__((ext_vector_type(8))) short;   // 8 bf16
using f4v = __attribute__((ext_vector_type(4))) float;   // 4 fp32
using u16x8 = __attribute__((ext_vector_type(8))) unsigned short;  // 16B

__device__ inline unsigned short f2bf(float f) {    // RNE fp32->bf16
    unsigned u = __float_as_uint(f);
    return (unsigned short)((u + 0x7FFFu + ((u >> 16) & 1u)) >> 16);
}
__device__ inline float bfh(unsigned short v) {
    return __uint_as_float((unsigned)v << 16);
}
__device__ inline unsigned long long pack_e(int meta, float c) {
    return (unsigned long long)(unsigned)meta |
           ((unsigned long long)(unsigned)__float_as_uint(c) << 32);
}

// Bin 4096 edges -> per-wave LDS histograms + shfl-scan counting-sort ->
// coalesced run writes. Entry u64 = {src:16 | dloc:8 | bucket:8 | coef:32}.
__global__ __launch_bounds__(512) void k_prep(const int* __restrict__ src,
                                              const int* __restrict__ dst,
                                              const float* __restrict__ ew,
                                              const float* __restrict__ pr,
                                              int* __restrict__ cur1,
                                              unsigned long long* __restrict__ stage) {
    int tid = threadIdx.x;
    int wv = tid >> 6, ln = tid & 63;
    __shared__ int h[8][256];                    // per-wave histograms, 8KB
    __shared__ int tot[256];                     // bin totals
    __shared__ int sc[256];                      // inclusive scan of tot
    __shared__ int gb[256];                      // global base per bucket
    __shared__ int wsum[4];                      // scan wave sums
    __shared__ unsigned long long sorted[EPB];   // 32 KB

    for (int i = ln; i < 256; i += 64) h[wv][i] = 0;  // own table: no barrier
    int base = blockIdx.x * EPB;
    int n = min(EPB, NE - base);

    unsigned long long ent[8]; int bkt[8]; int lrk[8];
    #pragma unroll
    for (int j = 0; j < 8; j++) {
        int e = base + j * 512 + tid;
        bkt[j] = -1;
        if (e < NE) {
            int d = dst[e];
            int s = src[e];
            float c = ew[e] * pr[s];
            int bk = d >> 8;
            bkt[j] = bk;
            lrk[j] = atomicAdd(&h[wv][bk], 1);   // own-wave table: 8x less contention
            ent[j] = pack_e(s | ((d & 255) << 16) | (bk << 24), c);
        }
    }
    __syncthreads();                             // B1: histograms complete
    int scv = 0;
    if (tid < 256) {
        int run = 0;                             // cross-wave prefix, in-place
        #pragma unroll
        for (int w = 0; w < 8; w++) { int v = h[w][tid]; h[w][tid] = run; run += v; }
        tot[tid] = run;
        scv = run;                               // wave-intrinsic inclusive scan
        #pragma unroll
        for (int o = 1; o < 64; o <<= 1) {
            int t = __shfl_up(scv, o);
            if (ln >= o) scv += t;
        }
        if (ln == 63) wsum[wv] = scv;
    }
    __syncthreads();                             // B2: wsum ready
    if (tid < 256) {
        int add = 0;
        #pragma unroll
        for (int w = 0; w < 4; w++) add += (w < wv) ? wsum[w] : 0;
        sc[tid] = scv + add;
    }
    if (tid < NB)
        gb[tid] = tot[tid] ? atomicAdd(&cur1[tid], tot[tid]) : 0;
    __syncthreads();                             // B3: sc/gb ready
    #pragma unroll
    for (int j = 0; j < 8; j++)
        if (bkt[j] >= 0)
            sorted[sc[bkt[j]] - tot[bkt[j]] + h[wv][bkt[j]] + lrk[j]] = ent[j];
    __syncthreads();                             // B4: sorted ready
    for (int i = tid; i < n; i += 512) {         // coalesced run writes
        unsigned long long e = sorted[i];
        int bk = ((int)(e >> 24)) & 0xff;
        stage[(size_t)bk * CAPB + gb[bk] + (i - (sc[bk] - tot[bk]))] = e;
    }
}

// Blocks [0,NB): per-bucket counting sort by dloc (per-wave hist + shfl
// scan); emits u32 {src | coef_bf16<<16} into first half of own region.
// Blocks [NB, NB+NCVT): y16 = bf16(x) streaming cvt.
// Block NB+NCVT: W -> bf16 pre-swizzled MFMA fragments (for k_gemm).
__global__ __launch_bounds__(512) void k_sortB(unsigned long long* __restrict__ stage,
                                               const int* __restrict__ cur1,
                                               int* __restrict__ offs,
                                               int* __restrict__ counts,
                                               const float4* __restrict__ x4,
                                               ushort4* __restrict__ y16v,
                                               const float* __restrict__ W,
                                               unsigned short* __restrict__ wfrag) {
    int tid = threadIdx.x;
    int blk = blockIdx.x;
    if (blk >= NB) {
        int ci = blk - NB;
        if (ci < NCVT) {                        // cvt phase
            int i = ci * 512 + tid;
            if (i < NN * DD / 4) {
                float4 v = x4[i];
                y16v[i] = make_ushort4(f2bf(v.x), f2bf(v.y), f2bf(v.z), f2bf(v.w));
            }
        } else {                                // W fragment phase (1 block)
            for (int i = tid; i < 18 * 512; i += 512) {
                int f = i >> 9, r = i & 511;
                int lane = r >> 3, j = r & 7;
                int ks = f / 6, nt = f - 6 * ks;
                int n = nt * 16 + (lane & 15);
                int k = ks * 32 + (lane >> 4) * 8 + j;
                wfrag[i] = f2bf(W[n * DD + k]);
            }
        }
        return;
    }
    int wv = tid >> 6, ln = tid & 63;
    __shared__ int h[8][256];                    // per-wave histograms, 8KB
    __shared__ int tot[256];
    __shared__ int sc[256];
    __shared__ int wsum[4];
    __shared__ unsigned sorted[CAPB];            // u32, 18.4 KB
    size_t base = (size_t)blk * CAPB;
    int n = cur1[blk];

    for (int i = ln; i < 256; i += 64) h[wv][i] = 0;  // own table: no barrier

    unsigned e32[9]; int dl[9]; int lrk[9];
    int m = 0;
    for (int i = tid; i < n; i += 512) {
        unsigned long long e = stage[base + i];
        int dloc = ((int)(e >> 16)) & 0xff;
        unsigned cb = (unsigned)(e >> 32);       // coef fp32 bits
        unsigned cbf = (cb + 0x7FFFu + ((cb >> 16) & 1u)) >> 16;  // bf16
        e32[m] = ((unsigned)e & 0xffffu) | (cbf << 16);
        dl[m] = dloc;
        lrk[m] = atomicAdd(&h[wv][dloc], 1);
        m++;
    }
    __syncthreads();                             // B1
    int scv = 0;
    if (tid < 256) {
        int run = 0;
        #pragma unroll
        for (int w = 0; w < 8; w++) { int v = h[w][tid]; h[w][tid] = run; run += v; }
        tot[tid] = run;
        scv = run;
        #pragma unroll
        for (int o = 1; o < 64; o <<= 1) {
            int t = __shfl_up(scv, o);
            if (ln >= o) scv += t;
        }
        if (ln == 63) wsum[wv] = scv;
    }
    __syncthreads();                             // B2
    if (tid < 256) {
        int add = 0;
        #pragma unroll
        for (int w = 0; w < 4; w++) add += (w < wv) ? wsum[w] : 0;
        sc[tid] = scv + add;
    }
    __syncthreads();                             // B3
    m = 0;
    for (int i = tid; i < n; i += 512) {
        int d = dl[m];
        sorted[sc[d] - tot[d] + h[wv][d] + lrk[m]] = e32[m];
        m++;
    }
    __syncthreads();                             // B4
    unsigned* outp = (unsigned*)(stage + base);  // first half of own region
    for (int i = tid; i < n; i += 512) outp[i] = sorted[i];
    if (tid < 256) {
        int d = (blk << 8) + tid;
        if (d < NN) {
            offs[d] = (int)(2 * base) + sc[tid] - tot[tid];   // u32 index
            counts[d] = tot[tid];
        }
    }
}

// Pull-aggregate (R16-verified): 8 nodes/block, lanes 0..11 own one ushort8
// (8 bf16 channels, 16B gather). Writes io16 = bf16(aggr + x). UNTOUCHED.
__global__ __launch_bounds__(256) void k_pull(const u16x8* __restrict__ y16v8,
                                              const float4* __restrict__ x4,
                                              const int* __restrict__ offs,
                                              const int* __restrict__ counts,
                                              const unsigned* __restrict__ ep,
                                              u16x8* __restrict__ io16v8) {
    int g = blockIdx.x * 8 + (threadIdx.x >> 5);
    int lane = threadIdx.x & 31;
    if (g >= NN || lane >= 12) return;
    int beg = offs[g];
    int deg = counts[g];
    float a0 = 0.f, a1 = 0.f, a2 = 0.f, a3 = 0.f;
    float a4 = 0.f, a5 = 0.f, a6 = 0.f, a7 = 0.f;
    int k = 0;
    for (; k + 8 <= deg; k += 8) {
        unsigned e[8];
        #pragma unroll
        for (int j = 0; j < 8; j++) e[j] = ep[beg + k + j];
        u16x8 u[8];
        #pragma unroll
        for (int j = 0; j < 8; j++)
            u[j] = y16v8[(size_t)(e[j] & 0xffff) * 12 + lane];
        #pragma unroll
        for (int j = 0; j < 8; j++) {
            float c = bfh((unsigned short)(e[j] >> 16));
            a0 += c * bfh(u[j][0]); a1 += c * bfh(u[j][1]);
            a2 += c * bfh(u[j][2]); a3 += c * bfh(u[j][3]);
            a4 += c * bfh(u[j][4]); a5 += c * bfh(u[j][5]);
            a6 += c * bfh(u[j][6]); a7 += c * bfh(u[j][7]);
        }
    }
    for (; k + 4 <= deg; k += 4) {
        unsigned e[4];
        #pragma unroll
        for (int j = 0; j < 4; j++) e[j] = ep[beg + k + j];
        u16x8 u[4];
        #pragma unroll
        for (int j = 0; j < 4; j++)
            u[j] = y16v8[(size_t)(e[j] & 0xffff) * 12 + lane];
        #pragma unroll
        for (int j = 0; j < 4; j++) {
            float c = bfh((unsigned short)(e[j] >> 16));
            a0 += c * bfh(u[j][0]); a1 += c * bfh(u[j][1]);
            a2 += c * bfh(u[j][2]); a3 += c * bfh(u[j][3]);
            a4 += c * bfh(u[j][4]); a5 += c * bfh(u[j][5]);
            a6 += c * bfh(u[j][6]); a7 += c * bfh(u[j][7]);
        }
    }
    for (; k < deg; k++) {
        unsigned e = ep[beg + k];
        u16x8 u = y16v8[(size_t)(e & 0xffff) * 12 + lane];
        float c = bfh((unsigned short)(e >> 16));
        a0 += c * bfh(u[0]); a1 += c * bfh(u[1]);
        a2 += c * bfh(u[2]); a3 += c * bfh(u[3]);
        a4 += c * bfh(u[4]); a5 += c * bfh(u[5]);
        a6 += c * bfh(u[6]); a7 += c * bfh(u[7]);
    }
    float4 xl = x4[(size_t)g * 24 + lane * 2];
    float4 xh = x4[(size_t)g * 24 + lane * 2 + 1];
    u16x8 o;
    o[0] = f2bf(a0 + xl.x); o[1] = f2bf(a1 + xl.y);
    o[2] = f2bf(a2 + xl.z); o[3] = f2bf(a3 + xl.w);
    o[4] = f2bf(a4 + xh.x); o[5] = f2bf(a5 + xh.y);
    o[6] = f2bf(a6 + xh.z); o[7] = f2bf(a7 + xh.w);
    io16v8[(size_t)g * 12 + lane] = o;
}

// MFMA GEMM: out[r,o] = sum_d io16[r,d]*W[o,d] + b[o], fp32 out.
// B-frags pre-swizzled in ws (wfrag), loaded coalesced 16B/lane from L2.
// C/D: col=lane&15, row=quad*4+reg (HW-verified; absmax-confirmed).
__global__ __launch_bounds__(256) void k_gemm(const unsigned short* __restrict__ io16,
                                              const unsigned short* __restrict__ wfrag,
                                              const float* __restrict__ b,
                                              float* __restrict__ out) {
    int tid = threadIdx.x;
    int wave = tid >> 6, lane = tid & 63;
    int quad = lane >> 4, m16 = lane & 15;
    int r0 = blockIdx.x * 64 + wave * 16;
    int rowa = r0 + m16;
    if (rowa >= NN) rowa = NN - 1;           // clamped A read, store masked

    const s8v* wf = (const s8v*)wfrag;       // frag (ks*6+nt) x 64 lanes

    f4v acc[6];
    #pragma unroll
    for (int nt = 0; nt < 6; nt++) acc[nt] = (f4v){0.f, 0.f, 0.f, 0.f};

    #pragma unroll
    for (int ks = 0; ks < 3; ks++) {
        s8v a = *(const s8v*)(io16 + (size_t)rowa * DD + ks * 32 + quad * 8);
        #pragma unroll
        for (int nt = 0; nt < 6; nt++) {
            s8v bb = wf[(ks * 6 + nt) * 64 + lane];
            acc[nt] = __builtin_amdgcn_mfma_f32_16x16x32_bf16(a, bb, acc[nt], 0, 0, 0);
        }
    }

    #pragma unroll
    for (int nt = 0; nt < 6; nt++) {
        float bias = b[nt * 16 + m16];
        #pragma unroll
        for (int reg = 0; reg < 4; reg++) {
            int rr = r0 + quad * 4 + reg;
            if (rr < NN)
                out[(size_t)rr * DD + nt * 16 + m16] = acc[nt][reg] + bias;
        }
    }
}

extern "C" void kernel_launch(void* const* d_in, const int* in_sizes, int n_in,
                              void* d_out, int out_size, void* d_ws, size_t ws_size,
                              hipStream_t stream) {
    const float* x  = (const float*)d_in[0];
    const int*   ei = (const int*)d_in[1];   // [2,E]: [0..E)=src, [E..2E)=dst
    const float* ew = (const float*)d_in[2];
    const float* pr = (const float*)d_in[3];
    const float* W  = (const float*)d_in[4];
    const float* b  = (const float*)d_in[5];
    float* out = (float*)d_out;

    // ws layout (~26.9 MB)
    unsigned long long* stage = (unsigned long long*)d_ws;       // NB*CAPB u64
    unsigned short* y16 = (unsigned short*)(stage + (size_t)NB * CAPB);  // 9.6MB
    int* cur1   = (int*)(y16 + (size_t)NN * DD);      // 196
    int* offs   = cur1 + NB;                          // 50000
    int* counts = offs + NN;                          // 50000
    unsigned short* io16 = (unsigned short*)(counts + NN);       // 9.6MB
    unsigned short* wfrag = io16 + (size_t)NN * DD;   // 18*512 bf16 = 18.4KB

    const int* src = ei;
    const int* dst = ei + NE;

    hipMemsetAsync(cur1, 0, NB * sizeof(int), stream);
    k_prep<<<NBLK, 512, 0, stream>>>(src, dst, ew, pr, cur1, stage);
    k_sortB<<<NB + NCVT + 1, 512, 0, stream>>>(stage, cur1, offs, counts,
                                               (const float4*)x, (ushort4*)y16,
                                               W, wfrag);
    k_pull<<<(NN + 7) / 8, 256, 0, stream>>>((const u16x8*)y16, (const float4*)x,
                                             offs, counts, (const unsigned*)stage,
                                             (u16x8*)io16);
    k_gemm<<<(NN + 63) / 64, 256, 0, stream>>>(io16, wfrag, b, out);
}